// Round 2
// baseline (2033.414 us; speedup 1.0000x reference)
//
#include <hip/hip_runtime.h>
#include <stdint.h>
#include <math.h>

// MetropolisHastingsSampler: 2176-step serial MH chain over a 512-dim walker
// with psi = MLP(512->1024 tanh ->1). Strategy:
//   K1 (parallel): bit-exact JAX threefry2x32 RNG (PARTITIONABLE mode, the
//       default since JAX 0.4.27) -> step deltas A[t+1]=0.1f*n_t, A[0]=x0,
//       uniforms U[t].
//   K2 (parallel): Z = A @ W1, f64 accumulate, f32 store. Z[0] = x0@W1.
//   K3 (1 block, 256 thr): sequential chain carrying y = x@W1 in f64 regs;
//       per step: y_cand = y + Z[t+1]; h=tanh; s=h@W2 (f64); accept; out x.
// Workspace: A (2177*512 f32) | Z (2177*1024 f32) | U (2176 f32)  ~= 12.8 MB.

#define T_TOTAL 2176
#define NBURN   128
#define DDIM    512
#define HDIM    1024

// ---------------- threefry2x32 (JAX-exact) ----------------
__device__ __forceinline__ uint2 tf2x32(uint32_t k0, uint32_t k1,
                                        uint32_t x0, uint32_t x1) {
  uint32_t ks2 = k0 ^ k1 ^ 0x1BD11BDAu;
  x0 += k0; x1 += k1;
#define TF_R(r) { x0 += x1; x1 = (x1 << (r)) | (x1 >> (32 - (r))); x1 ^= x0; }
  TF_R(13) TF_R(15) TF_R(26) TF_R(6)
  x0 += k1;  x1 += ks2 + 1u;
  TF_R(17) TF_R(29) TF_R(16) TF_R(24)
  x0 += ks2; x1 += k0 + 2u;
  TF_R(13) TF_R(15) TF_R(26) TF_R(6)
  x0 += k0;  x1 += k1 + 3u;
  TF_R(17) TF_R(29) TF_R(16) TF_R(24)
  x0 += k1;  x1 += ks2 + 4u;
  TF_R(13) TF_R(15) TF_R(26) TF_R(6)
  x0 += ks2; x1 += k0 + 5u;
#undef TF_R
  return make_uint2(x0, x1);
}

// ---------------- XLA ErfInv f32 (Giles polynomial, all-f32 like XLA) ------
__device__ __forceinline__ float erfinv_xla(float x) {
  float w = -log1pf(-x * x);
  float p;
  if (w < 5.0f) {
    w = w - 2.5f;
    p = 2.81022636e-08f;
    p = fmaf(p, w, 3.43273939e-07f);
    p = fmaf(p, w, -3.5233877e-06f);
    p = fmaf(p, w, -4.39150654e-06f);
    p = fmaf(p, w, 0.00021858087f);
    p = fmaf(p, w, -0.00125372503f);
    p = fmaf(p, w, -0.00417768164f);
    p = fmaf(p, w, 0.246640727f);
    p = fmaf(p, w, 1.50140941f);
  } else {
    w = sqrtf(w) - 3.0f;
    p = -0.000200214257f;
    p = fmaf(p, w, 0.000100950558f);
    p = fmaf(p, w, 0.00134934322f);
    p = fmaf(p, w, -0.00367342844f);
    p = fmaf(p, w, 0.00573950773f);
    p = fmaf(p, w, -0.0076224613f);
    p = fmaf(p, w, 0.00943887047f);
    p = fmaf(p, w, 1.00167406f);
    p = fmaf(p, w, 2.83297682f);
  }
  return p * x;
}

// jax.random.normal f32: u = uniform(lo, 1) with lo = nextafter(-1,0);
// n = float32(sqrt(2)) * erfinv(u). (maxval-minval) rounds to exactly 2.0f.
__device__ __forceinline__ float normal_from_bits(uint32_t bits) {
  const float lo = -0.99999994f;  // -(1 - 2^-24)
  float u01 = __uint_as_float(0x3f800000u | (bits >> 9)) - 1.0f;
  float v = u01 * 2.0f + lo;      // u01*2 exact -> fma or mul+add identical
  v = fmaxf(lo, v);
  return 1.41421356237309515f * erfinv_xla(v);  // literal rounds to f32 sqrt(2)
}

// ---------------- XLA/Eigen rational tanh (f32) ----------------
__device__ __forceinline__ float tanh_xla(float x) {
  float ax = fabsf(x);
  float xc = fminf(7.99881172180175781f, fmaxf(-7.99881172180175781f, x));
  float x2 = xc * xc;
  float np_;
  np_ = fmaf(x2, -2.76076847742355e-16f, 2.00018790482477e-13f);
  np_ = fmaf(x2, np_, -8.60467152213735e-11f);
  np_ = fmaf(x2, np_, 5.12229709037114e-08f);
  np_ = fmaf(x2, np_, 1.48572235717979e-05f);
  np_ = fmaf(x2, np_, 6.37261928875436e-04f);
  np_ = fmaf(x2, np_, 4.89352455891786e-03f);
  float num = xc * np_;
  float dp;
  dp = fmaf(x2, 1.19825839466702e-06f, 1.18534705686654e-04f);
  dp = fmaf(x2, dp, 2.26843463243900e-03f);
  dp = fmaf(x2, dp, 4.89352518554385e-03f);
  float r = num / dp;
  return (ax < 0.0004f) ? x : r;
}

// ---------------- K1: RNG (threefry PARTITIONABLE mode) ----------------
// keys = split(key(1), 2176)   -> key_t = (tf(0,1, 0,t).x0, tf(0,1, 0,t).x1)
// kn, ku = split(key_t)        -> kn = tf(key_t,0,0), ku = tf(key_t,0,1)
// noise bits elem i (i<512)    -> tf(kn, 0, i).x0 ^ .x1
// uniform bits (size 1)        -> tf(ku, 0, 0).x0 ^ .x1
__global__ void __launch_bounds__(256) rng_kernel(const float* __restrict__ x0,
                                                  float* __restrict__ A,
                                                  float* __restrict__ U) {
  const uint32_t t = blockIdx.x;
  const int tid = threadIdx.x;
  uint2 kt = tf2x32(0u, 1u, 0u, t);
  uint2 kn = tf2x32(kt.x, kt.y, 0u, 0u);
  uint2 e0 = tf2x32(kn.x, kn.y, 0u, (uint32_t)tid);
  uint2 e1 = tf2x32(kn.x, kn.y, 0u, (uint32_t)(tid + 256));
  float n0 = normal_from_bits(e0.x ^ e0.y);
  float n1 = normal_from_bits(e1.x ^ e1.y);
  float* Arow = A + (size_t)(t + 1) * DDIM;
  Arow[tid]       = n0 * 0.1f;   // ref's noise * STEP_SIZE (f32)
  Arow[tid + 256] = n1 * 0.1f;
  if (tid == 0) {
    uint2 ku = tf2x32(kt.x, kt.y, 0u, 1u);
    uint2 eu = tf2x32(ku.x, ku.y, 0u, 0u);
    U[t] = __uint_as_float(0x3f800000u | ((eu.x ^ eu.y) >> 9)) - 1.0f;
  }
  if (t == 0) {                  // A row 0 = x0 (for Z[0] = x0@W1)
    A[tid]       = x0[tid];
    A[tid + 256] = x0[tid + 256];
  }
}

// ---------------- K2: Z = A @ W1 (f64 accumulate) ----------------
__global__ void __launch_bounds__(256) gemm_kernel(const float* __restrict__ A,
                                                   const float* __restrict__ W1,
                                                   float* __restrict__ Z,
                                                   int nrows) {
  __shared__ __align__(16) float As[16][512];
  const int r0 = blockIdx.x * 16;
  const int c  = blockIdx.y * 256 + threadIdx.x;
  for (int idx = threadIdx.x; idx < 16 * 512; idx += 256) {
    int rr = idx >> 9, dd = idx & 511;
    int r = r0 + rr;
    As[rr][dd] = (r < nrows) ? A[(size_t)r * 512 + dd] : 0.0f;
  }
  __syncthreads();
  double acc[16];
#pragma unroll
  for (int r = 0; r < 16; ++r) acc[r] = 0.0;
  for (int d = 0; d < 512; d += 4) {
    double w0 = (double)W1[(size_t)d * 1024 + c];
    double w1 = (double)W1[(size_t)(d + 1) * 1024 + c];
    double w2 = (double)W1[(size_t)(d + 2) * 1024 + c];
    double w3 = (double)W1[(size_t)(d + 3) * 1024 + c];
#pragma unroll
    for (int r = 0; r < 16; ++r) {
      const float4 a4 = *(const float4*)&As[r][d];
      acc[r] += ((double)a4.x * w0 + (double)a4.y * w1) +
                ((double)a4.z * w2 + (double)a4.w * w3);
    }
  }
  const int rmax = (nrows - r0 < 16) ? (nrows - r0) : 16;
  for (int r = 0; r < rmax; ++r)
    Z[(size_t)(r0 + r) * 1024 + c] = (float)acc[r];
}

// ---------------- K3: sequential chain ----------------
// 1 block, 256 threads (4 waves). Thread owns H-cols 4t..4t+3 (y in f64 regs)
// and x-coords 2t, 2t+1. One __syncthreads per step (ping-pong partials);
// accept decision computed redundantly by every thread (uniform branch).
__global__ void __launch_bounds__(256) chain_kernel(
    const float* __restrict__ Z, const float* __restrict__ A,
    const float* __restrict__ U, const float* __restrict__ x0,
    const float* __restrict__ b1, const float* __restrict__ W2,
    const float* __restrict__ b2, float* __restrict__ out) {
  const int tid = threadIdx.x;
  const int lane = tid & 63;
  __shared__ __align__(16) double partials[2][4];

  const float4* Zv = (const float4*)Z;   // 256 float4 per H-row
  const float2* Av = (const float2*)A;   // 256 float2 per D-row

  const float4 w2v = ((const float4*)W2)[tid];
  const float4 b1v = ((const float4*)b1)[tid];
  const float b2v = b2[0];

  float4 zrow0 = Zv[tid];
  double y0 = (double)zrow0.x, y1 = (double)zrow0.y;
  double y2 = (double)zrow0.z, y3 = (double)zrow0.w;

  float xa = x0[2 * tid], xb = x0[2 * tid + 1];

  // initial p_old = psi2(x0)
  {
    float h0 = tanh_xla((float)y0 + b1v.x);
    float h1 = tanh_xla((float)y1 + b1v.y);
    float h2 = tanh_xla((float)y2 + b1v.z);
    float h3 = tanh_xla((float)y3 + b1v.w);
    double tm = ((double)h0 * (double)w2v.x + (double)h1 * (double)w2v.y) +
                ((double)h2 * (double)w2v.z + (double)h3 * (double)w2v.w);
#pragma unroll
    for (int off = 32; off > 0; off >>= 1) tm += __shfl_xor(tm, off, 64);
    if (lane == 0) partials[1][tid >> 6] = tm;
  }
  __syncthreads();
  double s0d = ((partials[1][0] + partials[1][1]) +
                (partials[1][2] + partials[1][3])) + (double)b2v;
  float s0 = (float)s0d;
  float p_old = s0 * s0;

  // rolling prefetch (depth 1) of next step's Z row / delta row / uniform
  float4 zc = Zv[256 + tid];
  float2 dc = Av[256 + tid];
  float uc = U[0];

  for (int t = 0; t < T_TOTAL; ++t) {
    float4 z = zc; float2 dd = dc; float u = uc;
    if (t < T_TOTAL - 1) {
      zc = Zv[(size_t)(t + 2) * 256 + tid];
      dc = Av[(size_t)(t + 2) * 256 + tid];
      uc = U[t + 1];
    }
    double c0 = y0 + (double)z.x;
    double c1 = y1 + (double)z.y;
    double c2 = y2 + (double)z.z;
    double c3 = y3 + (double)z.w;
    float g0 = tanh_xla((float)c0 + b1v.x);
    float g1 = tanh_xla((float)c1 + b1v.y);
    float g2 = tanh_xla((float)c2 + b1v.z);
    float g3 = tanh_xla((float)c3 + b1v.w);
    double tm = ((double)g0 * (double)w2v.x + (double)g1 * (double)w2v.y) +
                ((double)g2 * (double)w2v.z + (double)g3 * (double)w2v.w);
#pragma unroll
    for (int off = 32; off > 0; off >>= 1) tm += __shfl_xor(tm, off, 64);
    if (lane == 0) partials[t & 1][tid >> 6] = tm;
    __syncthreads();
    double sd = ((partials[t & 1][0] + partials[t & 1][1]) +
                 (partials[t & 1][2] + partials[t & 1][3])) + (double)b2v;
    float s = (float)sd;
    float pn = s * s;
    float ratio = fminf(pn / (p_old + 1e-12f), 1.0f);
    if (u < ratio) {   // uniform across block: cheap scalar branch
      p_old = pn;
      y0 = c0; y1 = c1; y2 = c2; y3 = c3;
      xa += dd.x; xb += dd.y;
    }
    if (t >= NBURN) {
      float2 o; o.x = xa; o.y = xb;
      *(float2*)(out + (size_t)(t - NBURN) * DDIM + 2 * tid) = o;
    }
  }
}

extern "C" void kernel_launch(void* const* d_in, const int* in_sizes, int n_in,
                              void* d_out, int out_size, void* d_ws, size_t ws_size,
                              hipStream_t stream) {
  const float* x0 = (const float*)d_in[0];
  const float* W1 = (const float*)d_in[1];
  const float* b1 = (const float*)d_in[2];
  const float* W2 = (const float*)d_in[3];
  const float* b2 = (const float*)d_in[4];
  float* out = (float*)d_out;

  char* ws = (char*)d_ws;
  // A: (2177 x 512) f32 = 4,458,496 B ; Z: (2177 x 1024) f32 = 8,916,992 B ;
  // U: 2176 f32 = 8,704 B. Total ~12.8 MB.
  float* A = (float*)ws;
  float* Z = (float*)(ws + 4458496);
  float* U = (float*)(ws + 4458496 + 8916992);

  rng_kernel<<<T_TOTAL, 256, 0, stream>>>(x0, A, U);
  gemm_kernel<<<dim3(137, 4), 256, 0, stream>>>(A, W1, Z, T_TOTAL + 1);
  chain_kernel<<<1, 256, 0, stream>>>(Z, A, U, x0, b1, W2, b2, out);
}

// Round 3
// 1480.956 us; speedup vs baseline: 1.3730x; 1.3730x over previous
//
#include <hip/hip_runtime.h>
#include <stdint.h>
#include <math.h>

// MetropolisHastingsSampler: 2176-step serial MH chain over a 512-dim walker
// with psi = MLP(512->1024 tanh ->1).
//   K1: bit-exact JAX threefry2x32 (partitionable mode) -> deltas A, uniforms U.
//   K2: Z = A @ W1 (f64 accumulate, f32 store), scalar-A / coalesced-W1.
//   K3: 1-block sequential chain; latency-optimized: DPP wave reduce (VALU,
//       ~6 cyc/hop) instead of f64 shfl butterfly (~120 cyc/hop LDS), f32 dot,
//       divide off the accept chain, b1 folded into f64 carry.
// Workspace: A (2177*512 f32) | Z (2177*1024 f32) | U (2176 f32) ~= 12.8 MB.

#define T_TOTAL 2176
#define NBURN   128
#define DDIM    512
#define HDIM    1024

// ---------------- threefry2x32 (JAX-exact) ----------------
__device__ __forceinline__ uint2 tf2x32(uint32_t k0, uint32_t k1,
                                        uint32_t x0, uint32_t x1) {
  uint32_t ks2 = k0 ^ k1 ^ 0x1BD11BDAu;
  x0 += k0; x1 += k1;
#define TF_R(r) { x0 += x1; x1 = (x1 << (r)) | (x1 >> (32 - (r))); x1 ^= x0; }
  TF_R(13) TF_R(15) TF_R(26) TF_R(6)
  x0 += k1;  x1 += ks2 + 1u;
  TF_R(17) TF_R(29) TF_R(16) TF_R(24)
  x0 += ks2; x1 += k0 + 2u;
  TF_R(13) TF_R(15) TF_R(26) TF_R(6)
  x0 += k0;  x1 += k1 + 3u;
  TF_R(17) TF_R(29) TF_R(16) TF_R(24)
  x0 += k1;  x1 += ks2 + 4u;
  TF_R(13) TF_R(15) TF_R(26) TF_R(6)
  x0 += ks2; x1 += k0 + 5u;
#undef TF_R
  return make_uint2(x0, x1);
}

// ---------------- XLA ErfInv f32 (Giles polynomial) ----------------
__device__ __forceinline__ float erfinv_xla(float x) {
  float w = -log1pf(-x * x);
  float p;
  if (w < 5.0f) {
    w = w - 2.5f;
    p = 2.81022636e-08f;
    p = fmaf(p, w, 3.43273939e-07f);
    p = fmaf(p, w, -3.5233877e-06f);
    p = fmaf(p, w, -4.39150654e-06f);
    p = fmaf(p, w, 0.00021858087f);
    p = fmaf(p, w, -0.00125372503f);
    p = fmaf(p, w, -0.00417768164f);
    p = fmaf(p, w, 0.246640727f);
    p = fmaf(p, w, 1.50140941f);
  } else {
    w = sqrtf(w) - 3.0f;
    p = -0.000200214257f;
    p = fmaf(p, w, 0.000100950558f);
    p = fmaf(p, w, 0.00134934322f);
    p = fmaf(p, w, -0.00367342844f);
    p = fmaf(p, w, 0.00573950773f);
    p = fmaf(p, w, -0.0076224613f);
    p = fmaf(p, w, 0.00943887047f);
    p = fmaf(p, w, 1.00167406f);
    p = fmaf(p, w, 2.83297682f);
  }
  return p * x;
}

__device__ __forceinline__ float normal_from_bits(uint32_t bits) {
  const float lo = -0.99999994f;  // -(1 - 2^-24)
  float u01 = __uint_as_float(0x3f800000u | (bits >> 9)) - 1.0f;
  float v = u01 * 2.0f + lo;
  v = fmaxf(lo, v);
  return 1.41421356237309515f * erfinv_xla(v);
}

// ---------------- XLA/Eigen rational tanh (f32) ----------------
// Tiny-|x| path dropped: rational form differs from x by <5e-11 there.
__device__ __forceinline__ float tanh_xla(float x) {
  float xc = fminf(7.99881172180175781f, fmaxf(-7.99881172180175781f, x));
  float x2 = xc * xc;
  float np_;
  np_ = fmaf(x2, -2.76076847742355e-16f, 2.00018790482477e-13f);
  np_ = fmaf(x2, np_, -8.60467152213735e-11f);
  np_ = fmaf(x2, np_, 5.12229709037114e-08f);
  np_ = fmaf(x2, np_, 1.48572235717979e-05f);
  np_ = fmaf(x2, np_, 6.37261928875436e-04f);
  np_ = fmaf(x2, np_, 4.89352455891786e-03f);
  float num = xc * np_;
  float dp;
  dp = fmaf(x2, 1.19825839466702e-06f, 1.18534705686654e-04f);
  dp = fmaf(x2, dp, 2.26843463243900e-03f);
  dp = fmaf(x2, dp, 4.89352518554385e-03f);
  return num / dp;
}

// ---------------- K1: RNG (threefry partitionable mode) ----------------
__global__ void __launch_bounds__(256) rng_kernel(const float* __restrict__ x0,
                                                  float* __restrict__ A,
                                                  float* __restrict__ U) {
  const uint32_t t = blockIdx.x;
  const int tid = threadIdx.x;
  uint2 kt = tf2x32(0u, 1u, 0u, t);
  uint2 kn = tf2x32(kt.x, kt.y, 0u, 0u);
  uint2 e0 = tf2x32(kn.x, kn.y, 0u, (uint32_t)tid);
  uint2 e1 = tf2x32(kn.x, kn.y, 0u, (uint32_t)(tid + 256));
  float n0 = normal_from_bits(e0.x ^ e0.y);
  float n1 = normal_from_bits(e1.x ^ e1.y);
  float* Arow = A + (size_t)(t + 1) * DDIM;
  Arow[tid]       = n0 * 0.1f;
  Arow[tid + 256] = n1 * 0.1f;
  if (tid == 0) {
    uint2 ku = tf2x32(kt.x, kt.y, 0u, 1u);
    uint2 eu = tf2x32(ku.x, ku.y, 0u, 0u);
    U[t] = __uint_as_float(0x3f800000u | ((eu.x ^ eu.y) >> 9)) - 1.0f;
  }
  if (t == 0) {
    A[tid]       = x0[tid];
    A[tid + 256] = x0[tid + 256];
  }
}

// ---------------- K2: Z = A @ W1 (f64 accumulate) ----------------
// A rows read wave-uniformly (scalar cache), W1 coalesced across lanes.
__global__ void __launch_bounds__(256) gemm_kernel(const float* __restrict__ A,
                                                   const float* __restrict__ W1,
                                                   float* __restrict__ Z,
                                                   int nrows) {
  const int r0 = blockIdx.x * 16;
  const int c  = blockIdx.y * 256 + threadIdx.x;
  double acc[16];
#pragma unroll
  for (int r = 0; r < 16; ++r) acc[r] = 0.0;
  for (int d = 0; d < 512; d += 4) {
    double w0 = (double)W1[(size_t)d * 1024 + c];
    double w1 = (double)W1[(size_t)(d + 1) * 1024 + c];
    double w2 = (double)W1[(size_t)(d + 2) * 1024 + c];
    double w3 = (double)W1[(size_t)(d + 3) * 1024 + c];
#pragma unroll
    for (int r = 0; r < 16; ++r) {
      int rr = r0 + r; if (rr >= nrows) rr = nrows - 1;   // uniform clamp
      const float4 a4 = *(const float4*)(A + (size_t)rr * 512 + d);
      acc[r] += ((double)a4.x * w0 + (double)a4.y * w1) +
                ((double)a4.z * w2 + (double)a4.w * w3);
    }
  }
  const int rmax = (nrows - r0 < 16) ? (nrows - r0) : 16;
  for (int r = 0; r < rmax; ++r)
    Z[(size_t)(r0 + r) * 1024 + c] = (float)acc[r];
}

// ---------------- DPP wave64 sum-reduce (result in lane 63) ----------------
// xor1, xor2 (quad_perm), row_half_mirror, row_mirror -> per-row16 totals;
// row_bcast15 + row_bcast31 fold rows -> lane 63 holds the wave total.
#define DPP_ADD(v, ctrl)                                                     \
  v += __int_as_float(__builtin_amdgcn_update_dpp(                           \
      0, __float_as_int(v), (ctrl), 0xF, 0xF, true))

__device__ __forceinline__ float wave_reduce_to_last(float v) {
  DPP_ADD(v, 0xB1);   // quad_perm [1,0,3,2]  : xor 1
  DPP_ADD(v, 0x4E);   // quad_perm [2,3,0,1]  : xor 2
  DPP_ADD(v, 0x141);  // row_half_mirror      : xor quads within 8
  DPP_ADD(v, 0x140);  // row_mirror           : fold 8-groups -> row16 total
  DPP_ADD(v, 0x142);  // row_bcast15          : rows 0+1, rows 2+3
  DPP_ADD(v, 0x143);  // row_bcast31          : all 4 rows (lanes 48-63)
  return v;           // lane 63 = wave total
}

// ---------------- K3: sequential chain ----------------
// 1 block, 256 threads (4 waves). Thread owns H-cols 4t..4t+3 with carry
// W = x@W1 + b1 in f64 regs, and x-coords 2t,2t+1. One barrier per step.
__global__ void __launch_bounds__(256) chain_kernel(
    const float* __restrict__ Z, const float* __restrict__ A,
    const float* __restrict__ U, const float* __restrict__ x0,
    const float* __restrict__ b1, const float* __restrict__ W2,
    const float* __restrict__ b2, float* __restrict__ out) {
  const int tid = threadIdx.x;
  const int lane = tid & 63;
  const int wid = tid >> 6;
  __shared__ __align__(16) float wsum[2][4];

  const float4* Zv = (const float4*)Z;   // 256 float4 per H-row
  const float2* Av = (const float2*)A;   // 256 float2 per D-row

  const float4 w2v = ((const float4*)W2)[tid];
  const float4 b1v = ((const float4*)b1)[tid];
  const float b2v = b2[0];

  // carry W = y + b1 (f64); init from Z row 0 = x0@W1
  float4 z0 = Zv[tid];
  double Y0 = (double)z0.x + (double)b1v.x;
  double Y1 = (double)z0.y + (double)b1v.y;
  double Y2 = (double)z0.z + (double)b1v.z;
  double Y3 = (double)z0.w + (double)b1v.w;

  float xa = x0[2 * tid], xb = x0[2 * tid + 1];

  // ---- prologue: p = psi2(x0) ----
  {
    float g0 = tanh_xla((float)Y0);
    float g1 = tanh_xla((float)Y1);
    float g2 = tanh_xla((float)Y2);
    float g3 = tanh_xla((float)Y3);
    float tm = fmaf(g3, w2v.w, fmaf(g2, w2v.z, fmaf(g1, w2v.y, g0 * w2v.x)));
    tm = wave_reduce_to_last(tm);
    if (lane == 63) wsum[1][wid] = tm;
  }
  __syncthreads();
  float4 pp = *(const float4*)wsum[1];
  float m0 = ((pp.x + pp.y) + (pp.z + pp.w)) + b2v;
  float p = m0 * m0;

  float un = U[0];
  float um = un * (p + 1e-12f);        // accept_0 iff um < q_0
  un = U[1];

  // candidate for decision 0: C = Y + Z row 1
  float4 zr1 = Zv[256 + tid];
  double C0 = Y0 + (double)zr1.x;
  double C1 = Y1 + (double)zr1.y;
  double C2 = Y2 + (double)zr1.z;
  double C3 = Y3 + (double)zr1.w;
  {
    float g0 = tanh_xla((float)C0);
    float g1 = tanh_xla((float)C1);
    float g2 = tanh_xla((float)C2);
    float g3 = tanh_xla((float)C3);
    float tm = fmaf(g3, w2v.w, fmaf(g2, w2v.z, fmaf(g1, w2v.y, g0 * w2v.x)));
    tm = wave_reduce_to_last(tm);
    if (lane == 63) wsum[0][wid] = tm;
  }
  float2 ddc = Av[256 + tid];          // A row 1 (delta of decision 0)
  float4 zc  = Zv[512 + tid];          // Z row 2 (candidate of decision 1)
  __syncthreads();

  for (int t = 0; t < T_TOTAL; ++t) {
    // partials for decision t
    const float4 p4 = *(const float4*)wsum[t & 1];
    float m = ((p4.x + p4.y) + (p4.z + p4.w)) + b2v;
    float q = m * m;
    bool acc = um < q;

    // state update
    Y0 = acc ? C0 : Y0;  Y1 = acc ? C1 : Y1;
    Y2 = acc ? C2 : Y2;  Y3 = acc ? C3 : Y3;
    p  = acc ? q : p;
    xa = acc ? xa + ddc.x : xa;
    xb = acc ? xb + ddc.y : xb;
    if (t >= NBURN) {
      float2 o; o.x = xa; o.y = xb;
      *(float2*)(out + (size_t)(t - NBURN) * DDIM + 2 * tid) = o;
    }
    um = un * (p + 1e-12f);            // for decision t+1

    // candidate for decision t+1: C = Y + Z row (t+2)  (zc prefetched)
    C0 = Y0 + (double)zc.x;
    C1 = Y1 + (double)zc.y;
    C2 = Y2 + (double)zc.z;
    C3 = Y3 + (double)zc.w;

    // prefetch for next iteration (guarded at tail)
    int zr = t + 3; if (zr > 2176) zr = 2176;
    int ar = t + 2; if (ar > 2176) ar = 2176;
    int ur = t + 2; if (ur > 2175) ur = 2175;
    float4 zc2 = Zv[(size_t)zr * 256 + tid];
    float2 dd2 = Av[(size_t)ar * 256 + tid];
    float  un2 = U[ur];

    // eval candidate
    float g0 = tanh_xla((float)C0);
    float g1 = tanh_xla((float)C1);
    float g2 = tanh_xla((float)C2);
    float g3 = tanh_xla((float)C3);
    float tm = fmaf(g3, w2v.w, fmaf(g2, w2v.z, fmaf(g1, w2v.y, g0 * w2v.x)));
    tm = wave_reduce_to_last(tm);
    if (lane == 63) wsum[(t + 1) & 1][wid] = tm;

    zc = zc2; ddc = dd2; un = un2;
    __syncthreads();
  }
}

extern "C" void kernel_launch(void* const* d_in, const int* in_sizes, int n_in,
                              void* d_out, int out_size, void* d_ws, size_t ws_size,
                              hipStream_t stream) {
  const float* x0 = (const float*)d_in[0];
  const float* W1 = (const float*)d_in[1];
  const float* b1 = (const float*)d_in[2];
  const float* W2 = (const float*)d_in[3];
  const float* b2 = (const float*)d_in[4];
  float* out = (float*)d_out;

  char* ws = (char*)d_ws;
  float* A = (float*)ws;
  float* Z = (float*)(ws + 4458496);
  float* U = (float*)(ws + 4458496 + 8916992);

  rng_kernel<<<T_TOTAL, 256, 0, stream>>>(x0, A, U);
  gemm_kernel<<<dim3(137, 4), 256, 0, stream>>>(A, W1, Z, T_TOTAL + 1);
  chain_kernel<<<1, 256, 0, stream>>>(Z, A, U, x0, b1, W2, b2, out);
}

// Round 4
// 1083.449 us; speedup vs baseline: 1.8768x; 1.3669x over previous
//
#include <hip/hip_runtime.h>
#include <stdint.h>
#include <math.h>

// MetropolisHastingsSampler: 2176-step serial MH chain over a 512-dim walker
// with psi = MLP(512->1024 tanh ->1).
//   K1: bit-exact JAX threefry2x32 (partitionable mode) -> deltas A, uniforms U.
//   K2: Z = A @ W1 (f64 accumulate, f32 store).
//   K3: 1-block sequential chain. Round-4: raw s_barrier (lgkmcnt-only wait;
//       __syncthreads' vmcnt(0) drain was costing a full LLC round-trip per
//       step), distance-2 prefetch via unroll-2 per-parity registers, rcp-based
//       tanh divide. Cross-wave data is LDS-only, so skipping the vmcnt drain
//       at the barrier is safe.
// Workspace: A (2177*512 f32) | Z (2177*1024 f32) | U (2176 f32) ~= 12.8 MB.

#define T_TOTAL 2176
#define NBURN   128
#define DDIM    512
#define HDIM    1024

// ---------------- threefry2x32 (JAX-exact) ----------------
__device__ __forceinline__ uint2 tf2x32(uint32_t k0, uint32_t k1,
                                        uint32_t x0, uint32_t x1) {
  uint32_t ks2 = k0 ^ k1 ^ 0x1BD11BDAu;
  x0 += k0; x1 += k1;
#define TF_R(r) { x0 += x1; x1 = (x1 << (r)) | (x1 >> (32 - (r))); x1 ^= x0; }
  TF_R(13) TF_R(15) TF_R(26) TF_R(6)
  x0 += k1;  x1 += ks2 + 1u;
  TF_R(17) TF_R(29) TF_R(16) TF_R(24)
  x0 += ks2; x1 += k0 + 2u;
  TF_R(13) TF_R(15) TF_R(26) TF_R(6)
  x0 += k0;  x1 += k1 + 3u;
  TF_R(17) TF_R(29) TF_R(16) TF_R(24)
  x0 += k1;  x1 += ks2 + 4u;
  TF_R(13) TF_R(15) TF_R(26) TF_R(6)
  x0 += ks2; x1 += k0 + 5u;
#undef TF_R
  return make_uint2(x0, x1);
}

// ---------------- XLA ErfInv f32 (Giles polynomial) ----------------
__device__ __forceinline__ float erfinv_xla(float x) {
  float w = -log1pf(-x * x);
  float p;
  if (w < 5.0f) {
    w = w - 2.5f;
    p = 2.81022636e-08f;
    p = fmaf(p, w, 3.43273939e-07f);
    p = fmaf(p, w, -3.5233877e-06f);
    p = fmaf(p, w, -4.39150654e-06f);
    p = fmaf(p, w, 0.00021858087f);
    p = fmaf(p, w, -0.00125372503f);
    p = fmaf(p, w, -0.00417768164f);
    p = fmaf(p, w, 0.246640727f);
    p = fmaf(p, w, 1.50140941f);
  } else {
    w = sqrtf(w) - 3.0f;
    p = -0.000200214257f;
    p = fmaf(p, w, 0.000100950558f);
    p = fmaf(p, w, 0.00134934322f);
    p = fmaf(p, w, -0.00367342844f);
    p = fmaf(p, w, 0.00573950773f);
    p = fmaf(p, w, -0.0076224613f);
    p = fmaf(p, w, 0.00943887047f);
    p = fmaf(p, w, 1.00167406f);
    p = fmaf(p, w, 2.83297682f);
  }
  return p * x;
}

__device__ __forceinline__ float normal_from_bits(uint32_t bits) {
  const float lo = -0.99999994f;  // -(1 - 2^-24)
  float u01 = __uint_as_float(0x3f800000u | (bits >> 9)) - 1.0f;
  float v = u01 * 2.0f + lo;
  v = fmaxf(lo, v);
  return 1.41421356237309515f * erfinv_xla(v);
}

// ---------------- XLA/Eigen rational tanh (f32), rcp divide ----------------
// rcp is ~1 ulp vs IEEE div; decision margins demonstrated (R3 passes vs
// f64-numpy ref) tolerate >=1e-6 relative, rcp adds ~1e-7.
__device__ __forceinline__ float tanh_xla(float x) {
  float xc = fminf(7.99881172180175781f, fmaxf(-7.99881172180175781f, x));
  float x2 = xc * xc;
  float np_;
  np_ = fmaf(x2, -2.76076847742355e-16f, 2.00018790482477e-13f);
  np_ = fmaf(x2, np_, -8.60467152213735e-11f);
  np_ = fmaf(x2, np_, 5.12229709037114e-08f);
  np_ = fmaf(x2, np_, 1.48572235717979e-05f);
  np_ = fmaf(x2, np_, 6.37261928875436e-04f);
  np_ = fmaf(x2, np_, 4.89352455891786e-03f);
  float num = xc * np_;
  float dp;
  dp = fmaf(x2, 1.19825839466702e-06f, 1.18534705686654e-04f);
  dp = fmaf(x2, dp, 2.26843463243900e-03f);
  dp = fmaf(x2, dp, 4.89352518554385e-03f);
  return num * __builtin_amdgcn_rcpf(dp);
}

// ---------------- K1: RNG (threefry partitionable mode) ----------------
__global__ void __launch_bounds__(256) rng_kernel(const float* __restrict__ x0,
                                                  float* __restrict__ A,
                                                  float* __restrict__ U) {
  const uint32_t t = blockIdx.x;
  const int tid = threadIdx.x;
  uint2 kt = tf2x32(0u, 1u, 0u, t);
  uint2 kn = tf2x32(kt.x, kt.y, 0u, 0u);
  uint2 e0 = tf2x32(kn.x, kn.y, 0u, (uint32_t)tid);
  uint2 e1 = tf2x32(kn.x, kn.y, 0u, (uint32_t)(tid + 256));
  float n0 = normal_from_bits(e0.x ^ e0.y);
  float n1 = normal_from_bits(e1.x ^ e1.y);
  float* Arow = A + (size_t)(t + 1) * DDIM;
  Arow[tid]       = n0 * 0.1f;
  Arow[tid + 256] = n1 * 0.1f;
  if (tid == 0) {
    uint2 ku = tf2x32(kt.x, kt.y, 0u, 1u);
    uint2 eu = tf2x32(ku.x, ku.y, 0u, 0u);
    U[t] = __uint_as_float(0x3f800000u | ((eu.x ^ eu.y) >> 9)) - 1.0f;
  }
  if (t == 0) {
    A[tid]       = x0[tid];
    A[tid + 256] = x0[tid + 256];
  }
}

// ---------------- K2: Z = A @ W1 (f64 accumulate) ----------------
__global__ void __launch_bounds__(256) gemm_kernel(const float* __restrict__ A,
                                                   const float* __restrict__ W1,
                                                   float* __restrict__ Z,
                                                   int nrows) {
  const int r0 = blockIdx.x * 16;
  const int c  = blockIdx.y * 256 + threadIdx.x;
  double acc[16];
#pragma unroll
  for (int r = 0; r < 16; ++r) acc[r] = 0.0;
  for (int d = 0; d < 512; d += 4) {
    double w0 = (double)W1[(size_t)d * 1024 + c];
    double w1 = (double)W1[(size_t)(d + 1) * 1024 + c];
    double w2 = (double)W1[(size_t)(d + 2) * 1024 + c];
    double w3 = (double)W1[(size_t)(d + 3) * 1024 + c];
#pragma unroll
    for (int r = 0; r < 16; ++r) {
      int rr = r0 + r; if (rr >= nrows) rr = nrows - 1;   // uniform clamp
      const float4 a4 = *(const float4*)(A + (size_t)rr * 512 + d);
      acc[r] += ((double)a4.x * w0 + (double)a4.y * w1) +
                ((double)a4.z * w2 + (double)a4.w * w3);
    }
  }
  const int rmax = (nrows - r0 < 16) ? (nrows - r0) : 16;
  for (int r = 0; r < rmax; ++r)
    Z[(size_t)(r0 + r) * 1024 + c] = (float)acc[r];
}

// ---------------- DPP wave64 sum-reduce (result in lane 63) ----------------
#define DPP_ADD(v, ctrl)                                                     \
  v += __int_as_float(__builtin_amdgcn_update_dpp(                           \
      0, __float_as_int(v), (ctrl), 0xF, 0xF, true))

__device__ __forceinline__ float wave_reduce_to_last(float v) {
  DPP_ADD(v, 0xB1);   // quad_perm xor1
  DPP_ADD(v, 0x4E);   // quad_perm xor2
  DPP_ADD(v, 0x141);  // row_half_mirror
  DPP_ADD(v, 0x140);  // row_mirror -> row16 totals
  DPP_ADD(v, 0x142);  // row_bcast15
  DPP_ADD(v, 0x143);  // row_bcast31 -> lane 63 wave total
  return v;
}

// Execution barrier with LDS-visibility only: do NOT drain vmcnt, so global
// prefetch loads stay in flight across the barrier. Safe here: cross-wave
// communication in the loop is exclusively through LDS (wsum).
#define BAR() asm volatile("s_waitcnt lgkmcnt(0)\n\ts_barrier" ::: "memory")

// ---------------- K3: sequential chain ----------------
// 1 block, 256 threads (4 waves). Thread owns H-cols 4t..4t+3 with carry
// Y = x@W1 + b1 in f64 regs, and x-coords 2t,2t+1. One raw barrier per step.
__global__ void __launch_bounds__(256) chain_kernel(
    const float* __restrict__ Z, const float* __restrict__ A,
    const float* __restrict__ U, const float* __restrict__ x0,
    const float* __restrict__ b1, const float* __restrict__ W2,
    const float* __restrict__ b2, float* __restrict__ out) {
  const int tid = threadIdx.x;
  const int lane = tid & 63;
  const int wid = tid >> 6;
  __shared__ __align__(16) float wsum[2][4];

  const float4* Zv = (const float4*)Z;   // 256 float4 per H-row
  const float2* Av = (const float2*)A;   // 256 float2 per D-row

  const float4 w2v = ((const float4*)W2)[tid];
  const float4 b1v = ((const float4*)b1)[tid];
  const float b2v = b2[0];

  // issue all prologue + steady-state buffer loads up front
  float4 z0r = Zv[tid];                  // Z row 0
  float4 zr1 = Zv[256 + tid];            // Z row 1 (candidate 0)
  float4 zS0 = Zv[512 + tid];            // Z row 2 (parity-0 buffer)
  float4 zS1 = Zv[768 + tid];            // Z row 3 (parity-1 buffer)
  float2 dS0 = Av[256 + tid];            // A row 1
  float2 dS1 = Av[512 + tid];            // A row 2
  float uu0 = U[0];
  float uS0 = U[1];
  float uS1 = U[2];

  double Y0 = (double)z0r.x + (double)b1v.x;
  double Y1 = (double)z0r.y + (double)b1v.y;
  double Y2 = (double)z0r.z + (double)b1v.z;
  double Y3 = (double)z0r.w + (double)b1v.w;

  float xa = x0[2 * tid], xb = x0[2 * tid + 1];

  // ---- prologue: p = psi2(x0) ----
  {
    float g0 = tanh_xla((float)Y0);
    float g1 = tanh_xla((float)Y1);
    float g2 = tanh_xla((float)Y2);
    float g3 = tanh_xla((float)Y3);
    float tm = fmaf(g3, w2v.w, fmaf(g2, w2v.z, fmaf(g1, w2v.y, g0 * w2v.x)));
    tm = wave_reduce_to_last(tm);
    if (lane == 63) wsum[1][wid] = tm;
  }
  __syncthreads();
  float4 pp = *(const float4*)wsum[1];
  float m0 = ((pp.x + pp.y) + (pp.z + pp.w)) + b2v;
  float p = m0 * m0;
  float um = uu0 * (p + 1e-12f);         // accept_0 iff um < q_0

  // candidate for decision 0: C = Y + Z row 1
  double C0 = Y0 + (double)zr1.x;
  double C1 = Y1 + (double)zr1.y;
  double C2 = Y2 + (double)zr1.z;
  double C3 = Y3 + (double)zr1.w;
  {
    float g0 = tanh_xla((float)C0);
    float g1 = tanh_xla((float)C1);
    float g2 = tanh_xla((float)C2);
    float g3 = tanh_xla((float)C3);
    float tm = fmaf(g3, w2v.w, fmaf(g2, w2v.z, fmaf(g1, w2v.y, g0 * w2v.x)));
    tm = wave_reduce_to_last(tm);
    if (lane == 63) wsum[0][wid] = tm;
  }
  __syncthreads();

  // Per-step macro. Consumes parity buffers ZB (Z row t+2), DB (A row t+1),
  // UB (U[t+1]); reissues them for t+2 (Z row t+4 / A row t+3 / U[t+3]).
#define STEP(t, ZB, DB, UB, W_CUR, W_NXT)                                    \
  {                                                                          \
    const float4 p4 = *(const float4*)wsum[W_CUR];                           \
    float m = ((p4.x + p4.y) + (p4.z + p4.w)) + b2v;                         \
    float q = m * m;                                                         \
    bool acc = um < q;                                                       \
    Y0 = acc ? C0 : Y0;  Y1 = acc ? C1 : Y1;                                 \
    Y2 = acc ? C2 : Y2;  Y3 = acc ? C3 : Y3;                                 \
    p  = acc ? q : p;                                                        \
    xa = acc ? xa + DB.x : xa;                                               \
    xb = acc ? xb + DB.y : xb;                                               \
    if ((t) >= NBURN) {                                                      \
      float2 o; o.x = xa; o.y = xb;                                          \
      *(float2*)(out + (size_t)((t) - NBURN) * DDIM + 2 * tid) = o;          \
    }                                                                        \
    um = UB * (p + 1e-12f);                                                  \
    C0 = Y0 + (double)ZB.x;                                                  \
    C1 = Y1 + (double)ZB.y;                                                  \
    C2 = Y2 + (double)ZB.z;                                                  \
    C3 = Y3 + (double)ZB.w;                                                  \
    {                                                                        \
      int zr = (t) + 4; if (zr > 2176) zr = 2176;                            \
      int ar = (t) + 3; if (ar > 2176) ar = 2176;                            \
      int ur = (t) + 3; if (ur > 2175) ur = 2175;                            \
      ZB = Zv[(size_t)zr * 256 + tid];                                       \
      DB = Av[(size_t)ar * 256 + tid];                                       \
      UB = U[ur];                                                            \
    }                                                                        \
    float g0 = tanh_xla((float)C0);                                          \
    float g1 = tanh_xla((float)C1);                                          \
    float g2 = tanh_xla((float)C2);                                          \
    float g3 = tanh_xla((float)C3);                                          \
    float tm = fmaf(g3, w2v.w, fmaf(g2, w2v.z, fmaf(g1, w2v.y, g0 * w2v.x)));\
    tm = wave_reduce_to_last(tm);                                            \
    if (lane == 63) wsum[W_NXT][wid] = tm;                                   \
    BAR();                                                                   \
  }

  for (int t = 0; t < T_TOTAL; t += 2) {
    STEP(t,     zS0, dS0, uS0, 0, 1);
    STEP(t + 1, zS1, dS1, uS1, 1, 0);
  }
#undef STEP
}

extern "C" void kernel_launch(void* const* d_in, const int* in_sizes, int n_in,
                              void* d_out, int out_size, void* d_ws, size_t ws_size,
                              hipStream_t stream) {
  const float* x0 = (const float*)d_in[0];
  const float* W1 = (const float*)d_in[1];
  const float* b1 = (const float*)d_in[2];
  const float* W2 = (const float*)d_in[3];
  const float* b2 = (const float*)d_in[4];
  float* out = (float*)d_out;

  char* ws = (char*)d_ws;
  float* A = (float*)ws;
  float* Z = (float*)(ws + 4458496);
  float* U = (float*)(ws + 4458496 + 8916992);

  rng_kernel<<<T_TOTAL, 256, 0, stream>>>(x0, A, U);
  gemm_kernel<<<dim3(137, 4), 256, 0, stream>>>(A, W1, Z, T_TOTAL + 1);
  chain_kernel<<<1, 256, 0, stream>>>(Z, A, U, x0, b1, W2, b2, out);
}